// Round 2
// baseline (229.821 us; speedup 1.0000x reference)
//
#include <hip/hip_runtime.h>
#include <stdint.h>

#define B_ 4
#define S_ 2048
#define E_ 1024
#define D_ 1024   // attention dim

typedef short  bf16x8 __attribute__((ext_vector_type(8)));
typedef float  f32x4  __attribute__((ext_vector_type(4)));

// fp32 -> bf16 round-to-nearest-even
static __device__ __forceinline__ unsigned short f2bf(float f) {
    unsigned int u = __float_as_uint(f);
    u += 0x7fffu + ((u >> 16) & 1u);
    return (unsigned short)(u >> 16);
}

// async global->LDS, 16B per lane. LDS dest = wave-uniform base + lane*16.
static __device__ __forceinline__ void async16(const unsigned short* g, unsigned short* l) {
    auto gp = (const __attribute__((address_space(1))) void*)(uintptr_t)g;
    auto lp = (__attribute__((address_space(3))) void*)(uintptr_t)l;
    __builtin_amdgcn_global_load_lds(gp, lp, 16, 0, 0);
}

// ---------------------------------------------------------------------------
// LDS sub-tile unit (BK=64): row = 128 B = 8 chunks of 16 B. XOR swizzle:
// global chunk q of row r -> LDS chunk q^(r&7). One staging issue covers 8
// rows: lane l -> row +(l>>3), global chunk (l&7)^(l>>3). Reader k-half s:
// chunk (s*4+quad)^(row&7). Conflict-free (verified: SQ_LDS_BANK_CONFLICT=0).
//
// R2: exp/pv were ~253 TF vs proj's 916 with the SAME inner loop. R1 proved
// declared occupancy is irrelevant when the grid has only 2.1 blocks/CU (544
// blocks) — the m97 structure's overlap comes from CO-RESIDENT BLOCKS (m132:
// 2-resident=508TF, 4-resident=874TF). Fix: 128x64 tiles (24 KB LDS, 6
// blocks/CU): exp -> 1088 blocks (4.25/CU), pv -> 1024 blocks (4/CU exact),
// heavy-first + deep residency replaces pair-balancing. rowpart slot = 64-col
// group (nt64): each wave's partial spans all 64 cols -> 32-slot layout kept.
// ---------------------------------------------------------------------------

// Kernel 0: fp32 -> bf16 convert (x -> xb, [Wk;Wq;Wv] -> Wb).
__global__ __launch_bounds__(256)
void convert_kernel(const float* __restrict__ x,  const float* __restrict__ Wk,
                    const float* __restrict__ Wq, const float* __restrict__ Wv,
                    unsigned short* __restrict__ xb, unsigned short* __restrict__ Wb)
{
    const long long idx = ((long long)blockIdx.x * 256 + threadIdx.x) * 4;
    const float* src; unsigned short* dst; long long off;
    if (idx < (long long)B_ * S_ * E_) {
        src = x; dst = xb; off = idx;
    } else {
        long long w = idx - (long long)B_ * S_ * E_;
        const int sel = (int)(w >> 20);          // 2^20 elems per W
        off = w & 1048575LL;
        src = (sel == 0) ? Wk : (sel == 1) ? Wq : Wv;
        dst = Wb + ((long long)sel << 20);
    }
    const float4 f = *(const float4*)(src + off);
    ushort4 u = { f2bf(f.x), f2bf(f.y), f2bf(f.z), f2bf(f.w) };
    *(ushort4*)(dst + off) = u;
}

// ---------------------------------------------------------------------------
// Kernel 1: projections (FROZEN — 916 TF, the m97 plateau; 4 blocks/CU gives
// implicit overlap). C[m,n] = sum_e xb[m,e]*Wb[n,e]. Grid (64 m FAST, 24 ny).
// ---------------------------------------------------------------------------
__global__ __launch_bounds__(256, 4)
void proj_kernel(const unsigned short* __restrict__ xb,
                 const unsigned short* __restrict__ Wb,
                 unsigned short* __restrict__ Qb,
                 unsigned short* __restrict__ Kb,
                 unsigned short* __restrict__ Vt)
{
    __shared__ __align__(16) unsigned short As[128 * 64];
    __shared__ __align__(16) unsigned short Bs[128 * 64];

    const int t    = threadIdx.x;
    const int m0   = blockIdx.x * 128;
    const int ny   = blockIdx.y;
    const int wsel = ny >> 3;
    const int nloc = (ny & 7) * 128;

    const int lane = t & 63, wave = t >> 6;
    const int l15 = lane & 15, quad = lane >> 4;
    const int wm = wave & 1, wn = wave >> 1;
    const int sr = lane >> 3;
    const int sq = ((lane & 7) ^ sr) * 8;
    const int l7 = l15 & 7;
    const int rcA0 = (wm * 64 + l15) * 64 + ((quad ^ l7) * 8);
    const int rcA1 = (wm * 64 + l15) * 64 + (((4 + quad) ^ l7) * 8);
    const int rcB0 = (wn * 64 + l15) * 64 + ((quad ^ l7) * 8);
    const int rcB1 = (wn * 64 + l15) * 64 + (((4 + quad) ^ l7) * 8);

    const unsigned short* gA = xb + (size_t)(m0 + wave * 32 + sr) * E_ + sq;
    const unsigned short* gB = Wb + (size_t)(ny * 128 + wave * 32 + sr) * E_ + sq;
    unsigned short* lA = &As[wave * 2048];
    unsigned short* lB = &Bs[wave * 2048];

    f32x4 acc[4][4];
    #pragma unroll
    for (int i = 0; i < 4; i++)
        #pragma unroll
        for (int j = 0; j < 4; j++) acc[i][j] = {0.f, 0.f, 0.f, 0.f};

    for (int k0 = 0; k0 < E_; k0 += 64) {
        __syncthreads();
        #pragma unroll
        for (int i = 0; i < 4; i++) {
            async16(gA + k0 + i * 8 * E_, lA + i * 512);
            async16(gB + k0 + i * 8 * E_, lB + i * 512);
        }
        __syncthreads();

        #pragma unroll
        for (int s = 0; s < 2; s++) {
            bf16x8 af[4], bfr[4];
            const int ra = s ? rcA1 : rcA0, rb = s ? rcB1 : rcB0;
            #pragma unroll
            for (int i = 0; i < 4; i++) af[i]  = *(const bf16x8*)&As[ra + i * 1024];
            #pragma unroll
            for (int j = 0; j < 4; j++) bfr[j] = *(const bf16x8*)&Bs[rb + j * 1024];
            #pragma unroll
            for (int i = 0; i < 4; i++)
                #pragma unroll
                for (int j = 0; j < 4; j++)
                    acc[i][j] = __builtin_amdgcn_mfma_f32_16x16x32_bf16(af[i], bfr[j], acc[i][j], 0, 0, 0);
        }
    }

    if (wsel == 0) {
        #pragma unroll
        for (int i = 0; i < 4; i++)
            #pragma unroll
            for (int j = 0; j < 4; j++) {
                const int gn = nloc + wn * 64 + j * 16 + l15;
                #pragma unroll
                for (int r = 0; r < 4; r++) {
                    const int gm = m0 + wm * 64 + i * 16 + quad * 4 + r;
                    Kb[(size_t)gm * D_ + gn] = f2bf(acc[i][j][r]);
                }
            }
    } else if (wsel == 1) {
        #pragma unroll
        for (int i = 0; i < 4; i++)
            #pragma unroll
            for (int j = 0; j < 4; j++) {
                const int gn = nloc + wn * 64 + j * 16 + l15;
                #pragma unroll
                for (int r = 0; r < 4; r++) {
                    const int gm = m0 + wm * 64 + i * 16 + quad * 4 + r;
                    Qb[(size_t)gm * D_ + gn] = f2bf(acc[i][j][r] * 0.03125f);
                }
            }
    } else {
        #pragma unroll
        for (int i = 0; i < 4; i++)
            #pragma unroll
            for (int j = 0; j < 4; j++) {
                const int s0 = m0 + wm * 64 + i * 16 + quad * 4;
                const int b  = s0 >> 11, sl = s0 & (S_ - 1);
                const int gn = nloc + wn * 64 + j * 16 + l15;
                ushort4 u = { f2bf(acc[i][j][0]), f2bf(acc[i][j][1]),
                              f2bf(acc[i][j][2]), f2bf(acc[i][j][3]) };
                *(ushort4*)&Vt[((size_t)(b << 10) + gn) * S_ + sl] = u;
            }
    }
}

// ---------------------------------------------------------------------------
// Kernel 2: E = exp(Qs K^T), causal, bf16 -> P. 128x64 tiles, BK=64, 24 KB
// LDS single-buffered, 6 blocks/CU. Grid (272 triangular tiles, B): 1088
// blocks, uniform 16 iters. Wave w: rows wave*32..+31, all 64 cols ->
// acc[2][4]; rowpart slot = nt (64-col group), partial complete per wave.
// Scores bounded (|s| ~< 2) -> no max-subtraction.
// ---------------------------------------------------------------------------
__global__ __launch_bounds__(256, 6)
void expscores_kernel(const unsigned short* __restrict__ Qb,
                      const unsigned short* __restrict__ Kb,
                      unsigned short* __restrict__ P,
                      float* __restrict__ rowpart)
{
    // triangular id -> (mt, nt): row mt has 2mt+2 tiles of 64 cols
    int rem = blockIdx.x, mt = 0;
    while (rem >= 2 * mt + 2) { rem -= 2 * mt + 2; mt++; }
    const int nt = rem;
    const int b  = blockIdx.y;
    const int m0 = mt * 128, n0 = nt * 64;

    __shared__ __align__(16) unsigned short As[128 * 64];  // Q tile
    __shared__ __align__(16) unsigned short Bs[64 * 64];   // K tile

    const int t = threadIdx.x;
    const int lane = t & 63, wave = t >> 6;
    const int l15 = lane & 15, quad = lane >> 4;
    const int sr = lane >> 3;
    const int sq = ((lane & 7) ^ sr) * 8;
    const int l7 = l15 & 7;

    const unsigned short* gQ = Qb + (size_t)b * S_ * D_ + (size_t)(m0 + sr) * D_ + sq;
    const unsigned short* gK = Kb + (size_t)b * S_ * D_ + (size_t)(n0 + sr) * D_ + sq;

    f32x4 acc[2][4];
    #pragma unroll
    for (int i = 0; i < 2; i++)
        #pragma unroll
        for (int j = 0; j < 4; j++) acc[i][j] = {0.f, 0.f, 0.f, 0.f};

    for (int kt = 0; kt < 16; kt++) {
        const int k0 = kt * 64;
        __syncthreads();
        // 24 staging units (16 A + 8 B), 6 per wave, unit = 8 rows x 64 k
        #pragma unroll
        for (int i = 0; i < 6; i++) {
            if (i < 4) {
                const int u = wave + i * 4;               // A units 0..15
                async16(gQ + (size_t)u * 8 * D_ + k0, &As[u * 512]);
            } else {
                const int u = wave + (i - 4) * 4;         // B units 0..7
                async16(gK + (size_t)u * 8 * D_ + k0, &Bs[u * 512]);
            }
        }
        __syncthreads();

        #pragma unroll
        for (int s = 0; s < 2; s++) {
            const int cs = ((s * 4 + quad) ^ l7) * 8;
            bf16x8 af[2], bfr[4];
            #pragma unroll
            for (int i = 0; i < 2; i++)
                af[i] = *(const bf16x8*)&As[(wave * 32 + i * 16 + l15) * 64 + cs];
            #pragma unroll
            for (int j = 0; j < 4; j++)
                bfr[j] = *(const bf16x8*)&Bs[(j * 16 + l15) * 64 + cs];
            #pragma unroll
            for (int i = 0; i < 2; i++)
                #pragma unroll
                for (int j = 0; j < 4; j++)
                    acc[i][j] = __builtin_amdgcn_mfma_f32_16x16x32_bf16(af[i], bfr[j], acc[i][j], 0, 0, 0);
        }
    }

    unsigned short* Pb = P + (size_t)b * S_ * S_;
    #pragma unroll
    for (int i = 0; i < 2; i++)
        #pragma unroll
        for (int j = 0; j < 4; j++) {
            const int gn = n0 + j * 16 + l15;
            #pragma unroll
            for (int r = 0; r < 4; r++) {
                const int gm = m0 + wave * 32 + i * 16 + quad * 4 + r;
                const float e = (gn <= gm) ? __expf(acc[i][j][r]) : 0.f;
                acc[i][j][r] = e;
                Pb[(size_t)gm * S_ + gn] = f2bf(e);
            }
        }

    float* rp = rowpart + ((size_t)b * 32 + nt) * S_;
    #pragma unroll
    for (int i = 0; i < 2; i++) {
        float rsub[4];
        #pragma unroll
        for (int r = 0; r < 4; r++) {
            float s = acc[i][0][r] + acc[i][1][r] + acc[i][2][r] + acc[i][3][r];
            #pragma unroll
            for (int off = 8; off; off >>= 1) s += __shfl_xor(s, off);
            rsub[r] = s;
        }
        if (l15 == 0) {
            #pragma unroll
            for (int r = 0; r < 4; r++)
                rp[m0 + wave * 32 + i * 16 + quad * 4 + r] = rsub[r];
        }
    }
}

// ---------------------------------------------------------------------------
// Kernel 3: out = (E @ V) / rowsum. 128x64 tiles, BK=64, 24 KB LDS, 6
// blocks/CU. Grid (16 nt64 FAST -> XCD Vt locality, 16 y, B) = 1024 blocks
// (4/CU exact); mt = 15-y heavy-first, niter = 2mt+2; deep residency does
// the balancing. rowsum after K-loop.
// ---------------------------------------------------------------------------
__global__ __launch_bounds__(256, 6)
void pv_kernel(const unsigned short* __restrict__ P,
               const unsigned short* __restrict__ Vt,
               const float* __restrict__ rowpart,
               float* __restrict__ out)
{
    const int nt = blockIdx.x;                // 64-col group of D
    const int mt = 15 - blockIdx.y;           // heavy-first
    const int b  = blockIdx.z;
    const int m0 = mt * 128, n0 = nt * 64;
    const int niter = 2 * mt + 2;             // kend = m0+128, BK=64

    __shared__ __align__(16) unsigned short As[128 * 64];  // P tile
    __shared__ __align__(16) unsigned short Bs[64 * 64];   // Vt tile

    const int t = threadIdx.x;
    const int lane = t & 63, wave = t >> 6;
    const int l15 = lane & 15, quad = lane >> 4;
    const int sr = lane >> 3;
    const int sq = ((lane & 7) ^ sr) * 8;
    const int l7 = l15 & 7;

    const unsigned short* gP = P  + (size_t)b * S_ * S_ + (size_t)(m0 + sr) * S_ + sq;
    const unsigned short* gV = Vt + (size_t)b * D_ * S_ + (size_t)(n0 + sr) * S_ + sq;

    f32x4 acc[2][4];
    #pragma unroll
    for (int i = 0; i < 2; i++)
        #pragma unroll
        for (int j = 0; j < 4; j++) acc[i][j] = {0.f, 0.f, 0.f, 0.f};

    for (int kt = 0; kt < niter; kt++) {
        const int k0 = kt * 64;
        __syncthreads();
        #pragma unroll
        for (int i = 0; i < 6; i++) {
            if (i < 4) {
                const int u = wave + i * 4;               // A units 0..15
                async16(gP + (size_t)u * 8 * S_ + k0, &As[u * 512]);
            } else {
                const int u = wave + (i - 4) * 4;         // B units 0..7
                async16(gV + (size_t)u * 8 * S_ + k0, &Bs[u * 512]);
            }
        }
        __syncthreads();

        #pragma unroll
        for (int s = 0; s < 2; s++) {
            const int cs = ((s * 4 + quad) ^ l7) * 8;
            bf16x8 af[2], bfr[4];
            #pragma unroll
            for (int i = 0; i < 2; i++)
                af[i] = *(const bf16x8*)&As[(wave * 32 + i * 16 + l15) * 64 + cs];
            #pragma unroll
            for (int j = 0; j < 4; j++)
                bfr[j] = *(const bf16x8*)&Bs[(j * 16 + l15) * 64 + cs];
            #pragma unroll
            for (int i = 0; i < 2; i++)
                #pragma unroll
                for (int j = 0; j < 4; j++)
                    acc[i][j] = __builtin_amdgcn_mfma_f32_16x16x32_bf16(af[i], bfr[j], acc[i][j], 0, 0, 0);
        }
    }

    // 1/rowsum for this wave's 32 rows (lane&31), off the critical front
    const int row32 = lane & 31;
    const float* rp = rowpart + (size_t)b * 32 * S_ + (m0 + wave * 32 + row32);
    float rsum = 0.f;
    for (int k = 0; k < niter; k++) rsum += rp[(size_t)k * S_];
    const float invr = 1.0f / rsum;

    #pragma unroll
    for (int i = 0; i < 2; i++) {
        #pragma unroll
        for (int r = 0; r < 4; r++) {
            const float vr = __shfl(invr, i * 16 + quad * 4 + r);  // lane 0..31
            const int gm = m0 + wave * 32 + i * 16 + quad * 4 + r;
            #pragma unroll
            for (int j = 0; j < 4; j++) {
                const int gn = n0 + j * 16 + l15;
                out[((size_t)b * S_ + gm) * D_ + gn] = rintf(acc[i][j][r] * vr * 1e4f) * 1e-4f;
            }
        }
    }
}

// ---------------------------------------------------------------------------
// Workspace (~85 MB):
//   [0,     16.7M)  Qb bf16 [4][2048][1024]
//   [16.7M, 33.5M)  Kb bf16
//   [33.5M, 50.3M)  Vt bf16 [4][1024][2048]
//   [50.3M, 83.9M)  P  bf16 [4][2048][2048]
//       xb (16.7M) + Wb (6.3M) overlay the start of P's region (dead before
//       expscores writes P).
//   [83.9M, +1M)    rowpart fp32 [4][32][2048]  (slot = 64-col group)
// ---------------------------------------------------------------------------
extern "C" void kernel_launch(void* const* d_in, const int* in_sizes, int n_in,
                              void* d_out, int out_size, void* d_ws, size_t ws_size,
                              hipStream_t stream)
{
    (void)in_sizes; (void)n_in; (void)out_size; (void)ws_size;
    const float* x  = (const float*)d_in[0];
    const float* Wk = (const float*)d_in[1];
    const float* Wq = (const float*)d_in[2];
    const float* Wv = (const float*)d_in[3];
    float* out = (float*)d_out;

    char* ws = (char*)d_ws;
    unsigned short* Qb = (unsigned short*)ws;
    unsigned short* Kb = Qb + (size_t)B_ * S_ * D_;
    unsigned short* Vt = Kb + (size_t)B_ * S_ * D_;
    unsigned short* P  = Vt + (size_t)B_ * D_ * S_;
    unsigned short* xb = P;                                  // overlay (dead early)
    unsigned short* Wb = xb + (size_t)B_ * S_ * E_;
    float* rowpart = (float*)(P + (size_t)B_ * S_ * S_);

    const int conv_blocks = (B_ * S_ * E_ + 3 * D_ * E_) / (256 * 4);  // 11264
    convert_kernel  <<<conv_blocks, 256, 0, stream>>>(x, Wk, Wq, Wv, xb, Wb);
    proj_kernel     <<<dim3(64, 24, 1),   256, 0, stream>>>(xb, Wb, Qb, Kb, Vt);
    expscores_kernel<<<dim3(272, B_, 1),  256, 0, stream>>>(Qb, Kb, P, rowpart);
    pv_kernel       <<<dim3(16, 16, B_),  256, 0, stream>>>(P, Vt, rowpart, out);
}

// Round 3
// 225.524 us; speedup vs baseline: 1.0191x; 1.0191x over previous
//
#include <hip/hip_runtime.h>
#include <stdint.h>

#define B_ 4
#define S_ 2048
#define E_ 1024
#define D_ 1024   // attention dim

typedef short  bf16x8 __attribute__((ext_vector_type(8)));
typedef float  f32x4  __attribute__((ext_vector_type(4)));

// fp32 -> bf16 round-to-nearest-even
static __device__ __forceinline__ unsigned short f2bf(float f) {
    unsigned int u = __float_as_uint(f);
    u += 0x7fffu + ((u >> 16) & 1u);
    return (unsigned short)(u >> 16);
}

// async global->LDS, 16B per lane. LDS dest = wave-uniform base + lane*16.
static __device__ __forceinline__ void async16(const unsigned short* g, unsigned short* l) {
    auto gp = (const __attribute__((address_space(1))) void*)(uintptr_t)g;
    auto lp = (__attribute__((address_space(3))) void*)(uintptr_t)l;
    __builtin_amdgcn_global_load_lds(gp, lp, 16, 0, 0);
}

// ---------------------------------------------------------------------------
// LDS sub-tile unit (BK=64): row = 128 B = 8 chunks of 16 B. XOR swizzle:
// global chunk q of row r -> LDS chunk q^(r&7). One staging issue covers 8
// rows: lane l -> row +(l>>3), global chunk (l&7)^(l>>3). Reader k-half s:
// chunk (s*4+quad)^(row&7). Conflict-free (SQ_LDS_BANK_CONFLICT=0 measured).
//
// R3: R2 (128x64 tiles) regressed 216->230: smaller tiles stage 1.5x more
// bytes/FLOP — tile shrink is the wrong way to raise residency. exp's real
// problem: 544 blocks = 2.1/CU, no queue depth. Fix: FAT KERNEL — merge the
// V-projection (512 blocks, dependency-free w.r.t. exp: V reads xb/Wb from
// convert, exp reads Qb/Kb from proj-KQ) into exp's grid as a second block
// role. 1056 uniform 16-iter blocks at 4/CU. proj shrinks to KQ (grid-y 16).
// The old xb/Wb-over-P overlay becomes a RACE in the fat kernel (projV reads
// xb while exp writes P) -> needs 108 MB un-overlaid workspace; host falls
// back to the R1 split path (overlay legal: P written after xb dead) if
// ws_size < 108 MB.
// ---------------------------------------------------------------------------

// Kernel 0: fp32 -> bf16 convert (x -> xb, [Wk;Wq;Wv] -> Wb).
__global__ __launch_bounds__(256)
void convert_kernel(const float* __restrict__ x,  const float* __restrict__ Wk,
                    const float* __restrict__ Wq, const float* __restrict__ Wv,
                    unsigned short* __restrict__ xb, unsigned short* __restrict__ Wb)
{
    const long long idx = ((long long)blockIdx.x * 256 + threadIdx.x) * 4;
    const float* src; unsigned short* dst; long long off;
    if (idx < (long long)B_ * S_ * E_) {
        src = x; dst = xb; off = idx;
    } else {
        long long w = idx - (long long)B_ * S_ * E_;
        const int sel = (int)(w >> 20);          // 2^20 elems per W
        off = w & 1048575LL;
        src = (sel == 0) ? Wk : (sel == 1) ? Wq : Wv;
        dst = Wb + ((long long)sel << 20);
    }
    const float4 f = *(const float4*)(src + off);
    ushort4 u = { f2bf(f.x), f2bf(f.y), f2bf(f.z), f2bf(f.w) };
    *(ushort4*)(dst + off) = u;
}

// ---------------------------------------------------------------------------
// Kernel 1: projections (FROZEN m97 loop — 916 TF). C[m,n]=sum_e xb[m,e]Wb[n,e].
// Grid (64 m FAST, ny): ny<8 -> K, 8..15 -> Q, 16..23 -> V. Fat path launches
// ny=16 (KQ only; V moves to the fat kernel); fallback launches ny=24.
// ---------------------------------------------------------------------------
__global__ __launch_bounds__(256, 4)
void proj_kernel(const unsigned short* __restrict__ xb,
                 const unsigned short* __restrict__ Wb,
                 unsigned short* __restrict__ Qb,
                 unsigned short* __restrict__ Kb,
                 unsigned short* __restrict__ Vt)
{
    __shared__ __align__(16) unsigned short As[128 * 64];
    __shared__ __align__(16) unsigned short Bs[128 * 64];

    const int t    = threadIdx.x;
    const int m0   = blockIdx.x * 128;
    const int ny   = blockIdx.y;
    const int wsel = ny >> 3;
    const int nloc = (ny & 7) * 128;

    const int lane = t & 63, wave = t >> 6;
    const int l15 = lane & 15, quad = lane >> 4;
    const int wm = wave & 1, wn = wave >> 1;
    const int sr = lane >> 3;
    const int sq = ((lane & 7) ^ sr) * 8;
    const int l7 = l15 & 7;
    const int rcA0 = (wm * 64 + l15) * 64 + ((quad ^ l7) * 8);
    const int rcA1 = (wm * 64 + l15) * 64 + (((4 + quad) ^ l7) * 8);
    const int rcB0 = (wn * 64 + l15) * 64 + ((quad ^ l7) * 8);
    const int rcB1 = (wn * 64 + l15) * 64 + (((4 + quad) ^ l7) * 8);

    const unsigned short* gA = xb + (size_t)(m0 + wave * 32 + sr) * E_ + sq;
    const unsigned short* gB = Wb + (size_t)(ny * 128 + wave * 32 + sr) * E_ + sq;
    unsigned short* lA = &As[wave * 2048];
    unsigned short* lB = &Bs[wave * 2048];

    f32x4 acc[4][4];
    #pragma unroll
    for (int i = 0; i < 4; i++)
        #pragma unroll
        for (int j = 0; j < 4; j++) acc[i][j] = {0.f, 0.f, 0.f, 0.f};

    for (int k0 = 0; k0 < E_; k0 += 64) {
        __syncthreads();
        #pragma unroll
        for (int i = 0; i < 4; i++) {
            async16(gA + k0 + i * 8 * E_, lA + i * 512);
            async16(gB + k0 + i * 8 * E_, lB + i * 512);
        }
        __syncthreads();

        #pragma unroll
        for (int s = 0; s < 2; s++) {
            bf16x8 af[4], bfr[4];
            const int ra = s ? rcA1 : rcA0, rb = s ? rcB1 : rcB0;
            #pragma unroll
            for (int i = 0; i < 4; i++) af[i]  = *(const bf16x8*)&As[ra + i * 1024];
            #pragma unroll
            for (int j = 0; j < 4; j++) bfr[j] = *(const bf16x8*)&Bs[rb + j * 1024];
            #pragma unroll
            for (int i = 0; i < 4; i++)
                #pragma unroll
                for (int j = 0; j < 4; j++)
                    acc[i][j] = __builtin_amdgcn_mfma_f32_16x16x32_bf16(af[i], bfr[j], acc[i][j], 0, 0, 0);
        }
    }

    if (wsel == 0) {
        #pragma unroll
        for (int i = 0; i < 4; i++)
            #pragma unroll
            for (int j = 0; j < 4; j++) {
                const int gn = nloc + wn * 64 + j * 16 + l15;
                #pragma unroll
                for (int r = 0; r < 4; r++) {
                    const int gm = m0 + wm * 64 + i * 16 + quad * 4 + r;
                    Kb[(size_t)gm * D_ + gn] = f2bf(acc[i][j][r]);
                }
            }
    } else if (wsel == 1) {
        #pragma unroll
        for (int i = 0; i < 4; i++)
            #pragma unroll
            for (int j = 0; j < 4; j++) {
                const int gn = nloc + wn * 64 + j * 16 + l15;
                #pragma unroll
                for (int r = 0; r < 4; r++) {
                    const int gm = m0 + wm * 64 + i * 16 + quad * 4 + r;
                    Qb[(size_t)gm * D_ + gn] = f2bf(acc[i][j][r] * 0.03125f);
                }
            }
    } else {
        #pragma unroll
        for (int i = 0; i < 4; i++)
            #pragma unroll
            for (int j = 0; j < 4; j++) {
                const int s0 = m0 + wm * 64 + i * 16 + quad * 4;
                const int b  = s0 >> 11, sl = s0 & (S_ - 1);
                const int gn = nloc + wn * 64 + j * 16 + l15;
                ushort4 u = { f2bf(acc[i][j][0]), f2bf(acc[i][j][1]),
                              f2bf(acc[i][j][2]), f2bf(acc[i][j][3]) };
                *(ushort4*)&Vt[((size_t)(b << 10) + gn) * S_ + sl] = u;
            }
    }
}

// ---------------------------------------------------------------------------
// Kernel 2 (FAT): 1056 uniform blocks, 32 KB LDS, 4/CU.
//   bx < 544 : exp role — E = exp(Qs K^T), causal, 128x128 tile (mt,nt)
//              compact-triangular per batch (136 tiles), writes P + rowpart.
//   bx >= 544: projV role — V = xb @ Wv^T 128x128 tile, writes Vt transposed.
// Both roles run the identical 16-iter m97 K-loop (row stride 1024).
// ---------------------------------------------------------------------------
__global__ __launch_bounds__(256, 4)
void fat_kernel(const unsigned short* __restrict__ Qb,
                const unsigned short* __restrict__ Kb,
                const unsigned short* __restrict__ xb,
                const unsigned short* __restrict__ Wb,
                unsigned short* __restrict__ P,
                float* __restrict__ rowpart,
                unsigned short* __restrict__ Vt)
{
    __shared__ __align__(16) unsigned short As[128 * 64];
    __shared__ __align__(16) unsigned short Bs[128 * 64];

    const int bx = blockIdx.x;
    const bool is_exp = bx < 544;

    const int t = threadIdx.x;
    const int lane = t & 63, wave = t >> 6;
    const int l15 = lane & 15, quad = lane >> 4;
    const int wm = wave & 1, wn = wave >> 1;
    const int sr = lane >> 3;
    const int sq = ((lane & 7) ^ sr) * 8;
    const int l7 = l15 & 7;

    int b = 0, mt = 0, nt = 0, mb = 0, nb = 0;
    const unsigned short* gA;
    const unsigned short* gB;
    if (is_exp) {
        b = bx >> 7;                      // bx/136 would be exact; use div below
        // exact decode: b = bx / 136, tri = bx % 136
        b = bx / 136;
        int rem = bx - b * 136;
        mt = 0;
        while (rem >= mt + 1) { rem -= mt + 1; mt++; }
        nt = rem;
        gA = Qb + (size_t)b * S_ * D_ + (size_t)(mt * 128 + wave * 32 + sr) * D_ + sq;
        gB = Kb + (size_t)b * S_ * D_ + (size_t)(nt * 128 + wave * 32 + sr) * D_ + sq;
    } else {
        const int idx = bx - 544;
        mb = idx & 63;                    // 64 m-tiles (8192 rows)
        nb = idx >> 6;                    // 8 n-tiles (1024 V cols)
        gA = xb + (size_t)(mb * 128 + wave * 32 + sr) * E_ + sq;
        gB = Wb + ((size_t)2 << 20) + (size_t)(nb * 128 + wave * 32 + sr) * E_ + sq;
    }
    unsigned short* lA = &As[wave * 2048];
    unsigned short* lB = &Bs[wave * 2048];

    f32x4 acc[4][4];
    #pragma unroll
    for (int i = 0; i < 4; i++)
        #pragma unroll
        for (int j = 0; j < 4; j++) acc[i][j] = {0.f, 0.f, 0.f, 0.f};

    for (int k0 = 0; k0 < 1024; k0 += 64) {
        __syncthreads();
        #pragma unroll
        for (int i = 0; i < 4; i++) {
            async16(gA + k0 + i * 8 * 1024, lA + i * 512);
            async16(gB + k0 + i * 8 * 1024, lB + i * 512);
        }
        __syncthreads();

        #pragma unroll
        for (int s = 0; s < 2; s++) {
            const int cs = ((s * 4 + quad) ^ l7) * 8;
            bf16x8 af[4], bfr[4];
            #pragma unroll
            for (int i = 0; i < 4; i++)
                af[i] = *(const bf16x8*)&As[(wm * 64 + i * 16 + l15) * 64 + cs];
            #pragma unroll
            for (int j = 0; j < 4; j++)
                bfr[j] = *(const bf16x8*)&Bs[(wn * 64 + j * 16 + l15) * 64 + cs];
            #pragma unroll
            for (int i = 0; i < 4; i++)
                #pragma unroll
                for (int j = 0; j < 4; j++)
                    acc[i][j] = __builtin_amdgcn_mfma_f32_16x16x32_bf16(af[i], bfr[j], acc[i][j], 0, 0, 0);
        }
    }

    if (is_exp) {
        const int m0 = mt * 128, n0 = nt * 128;
        unsigned short* Pb = P + (size_t)b * S_ * S_;
        #pragma unroll
        for (int i = 0; i < 4; i++)
            #pragma unroll
            for (int j = 0; j < 4; j++) {
                const int gn = n0 + wn * 64 + j * 16 + l15;
                #pragma unroll
                for (int r = 0; r < 4; r++) {
                    const int gm = m0 + wm * 64 + i * 16 + quad * 4 + r;
                    const float e = (gn <= gm) ? __expf(acc[i][j][r]) : 0.f;
                    acc[i][j][r] = e;
                    Pb[(size_t)gm * S_ + gn] = f2bf(e);
                }
            }

        float* rp = rowpart + ((size_t)b * 32 + nt * 2 + wn) * S_;
        #pragma unroll
        for (int i = 0; i < 4; i++) {
            float rsub[4];
            #pragma unroll
            for (int r = 0; r < 4; r++) {
                float s = acc[i][0][r] + acc[i][1][r] + acc[i][2][r] + acc[i][3][r];
                #pragma unroll
                for (int off = 8; off; off >>= 1) s += __shfl_xor(s, off);
                rsub[r] = s;
            }
            if (l15 == 0) {
                #pragma unroll
                for (int r = 0; r < 4; r++)
                    rp[m0 + wm * 64 + i * 16 + quad * 4 + r] = rsub[r];
            }
        }
    } else {
        #pragma unroll
        for (int i = 0; i < 4; i++)
            #pragma unroll
            for (int j = 0; j < 4; j++) {
                const int s0 = mb * 128 + wm * 64 + i * 16 + quad * 4;
                const int vb = s0 >> 11, sl = s0 & (S_ - 1);
                const int gn = nb * 128 + wn * 64 + j * 16 + l15;
                ushort4 u = { f2bf(acc[i][j][0]), f2bf(acc[i][j][1]),
                              f2bf(acc[i][j][2]), f2bf(acc[i][j][3]) };
                *(ushort4*)&Vt[((size_t)(vb << 10) + gn) * S_ + sl] = u;
            }
    }
}

// ---------------------------------------------------------------------------
// Kernel 2b (fallback, R1): E = exp(Qs K^T) standalone. 128x128, single-buf
// 32 KB. Grid (16 nt FAST, 16 mt, B), early exit nt>mt, mt=15-y heavy-first.
// ---------------------------------------------------------------------------
__global__ __launch_bounds__(256, 4)
void expscores_kernel(const unsigned short* __restrict__ Qb,
                      const unsigned short* __restrict__ Kb,
                      unsigned short* __restrict__ P,
                      float* __restrict__ rowpart)
{
    const int nt = blockIdx.x;
    const int mt = 15 - blockIdx.y;
    const int b  = blockIdx.z;
    if (nt > mt) return;

    __shared__ __align__(16) unsigned short As[128 * 64];
    __shared__ __align__(16) unsigned short Bs[128 * 64];

    const int t = threadIdx.x;
    const int m0 = mt * 128, n0 = nt * 128;

    const int lane = t & 63, wave = t >> 6;
    const int l15 = lane & 15, quad = lane >> 4;
    const int wm = wave & 1, wn = wave >> 1;
    const int sr = lane >> 3;
    const int sq = ((lane & 7) ^ sr) * 8;
    const int l7 = l15 & 7;

    const unsigned short* gA = Qb + (size_t)b * S_ * D_ + (size_t)(m0 + wave * 32 + sr) * D_ + sq;
    const unsigned short* gB = Kb + (size_t)b * S_ * D_ + (size_t)(n0 + wave * 32 + sr) * D_ + sq;
    unsigned short* lA = &As[wave * 2048];
    unsigned short* lB = &Bs[wave * 2048];

    f32x4 acc[4][4];
    #pragma unroll
    for (int i = 0; i < 4; i++)
        #pragma unroll
        for (int j = 0; j < 4; j++) acc[i][j] = {0.f, 0.f, 0.f, 0.f};

    for (int kt = 0; kt < 16; kt++) {
        const int k0 = kt * 64;
        __syncthreads();
        #pragma unroll
        for (int i = 0; i < 4; i++) {
            async16(gA + k0 + i * 8 * D_, lA + i * 512);
            async16(gB + k0 + i * 8 * D_, lB + i * 512);
        }
        __syncthreads();

        #pragma unroll
        for (int s = 0; s < 2; s++) {
            const int cs = ((s * 4 + quad) ^ l7) * 8;
            bf16x8 af[4], bfr[4];
            #pragma unroll
            for (int i = 0; i < 4; i++)
                af[i] = *(const bf16x8*)&As[(wm * 64 + i * 16 + l15) * 64 + cs];
            #pragma unroll
            for (int j = 0; j < 4; j++)
                bfr[j] = *(const bf16x8*)&Bs[(wn * 64 + j * 16 + l15) * 64 + cs];
            #pragma unroll
            for (int i = 0; i < 4; i++)
                #pragma unroll
                for (int j = 0; j < 4; j++)
                    acc[i][j] = __builtin_amdgcn_mfma_f32_16x16x32_bf16(af[i], bfr[j], acc[i][j], 0, 0, 0);
        }
    }

    unsigned short* Pb = P + (size_t)b * S_ * S_;
    #pragma unroll
    for (int i = 0; i < 4; i++)
        #pragma unroll
        for (int j = 0; j < 4; j++) {
            const int gn = n0 + wn * 64 + j * 16 + l15;
            #pragma unroll
            for (int r = 0; r < 4; r++) {
                const int gm = m0 + wm * 64 + i * 16 + quad * 4 + r;
                const float e = (gn <= gm) ? __expf(acc[i][j][r]) : 0.f;
                acc[i][j][r] = e;
                Pb[(size_t)gm * S_ + gn] = f2bf(e);
            }
        }

    float* rp = rowpart + ((size_t)b * 32 + nt * 2 + wn) * S_;
    #pragma unroll
    for (int i = 0; i < 4; i++) {
        float rsub[4];
        #pragma unroll
        for (int r = 0; r < 4; r++) {
            float s = acc[i][0][r] + acc[i][1][r] + acc[i][2][r] + acc[i][3][r];
            #pragma unroll
            for (int off = 8; off; off >>= 1) s += __shfl_xor(s, off);
            rsub[r] = s;
        }
        if (l15 == 0) {
            #pragma unroll
            for (int r = 0; r < 4; r++)
                rp[m0 + wm * 64 + i * 16 + quad * 4 + r] = rsub[r];
        }
    }
}

// ---------------------------------------------------------------------------
// Kernel 3: out = (E @ V) / rowsum. 128x128 tile, BK=64, DOUBLE-BUFFERED
// (LDS 64 KB, 2 blocks/CU). Grid (8 nt FAST, 16 y, B); mt = (b&2)?y:15-y so
// co-resident pairs (c, c+256) have complementary iteration counts ->
// uniform 36 iters/CU. rowsum after K-loop.
// ---------------------------------------------------------------------------
__global__ __launch_bounds__(256, 2)
void pv_kernel(const unsigned short* __restrict__ P,
               const unsigned short* __restrict__ Vt,
               const float* __restrict__ rowpart,
               float* __restrict__ out)
{
    const int nt = blockIdx.x;
    const int yy = blockIdx.y;
    const int b  = blockIdx.z;
    const int mt = (b & 2) ? yy : (15 - yy);  // complementary pairing across b

    __shared__ __align__(16) unsigned short As[2 * 128 * 64];
    __shared__ __align__(16) unsigned short Bs[2 * 128 * 64];

    const int t = threadIdx.x;
    const int m0 = mt * 128, n0 = nt * 128;
    const int niter = 2 * mt + 2;             // kend = m0+128, BK=64

    const int lane = t & 63, wave = t >> 6;
    const int l15 = lane & 15, quad = lane >> 4;
    const int wm = wave & 1, wn = wave >> 1;
    const int sr = lane >> 3;
    const int sq = ((lane & 7) ^ sr) * 8;
    const int l7 = l15 & 7;

    const unsigned short* gA = P  + (size_t)b * S_ * S_ + (size_t)(m0 + wave * 32 + sr) * S_ + sq;
    const unsigned short* gB = Vt + (size_t)b * D_ * S_ + (size_t)(n0 + wave * 32 + sr) * S_ + sq;
    unsigned short* lA = &As[wave * 2048];
    unsigned short* lB = &Bs[wave * 2048];

    f32x4 acc[4][4];
    #pragma unroll
    for (int i = 0; i < 4; i++)
        #pragma unroll
        for (int j = 0; j < 4; j++) acc[i][j] = {0.f, 0.f, 0.f, 0.f};

    // prologue: stage k=0 into buffer 0
    #pragma unroll
    for (int i = 0; i < 4; i++) {
        async16(gA + i * 8 * S_, lA + i * 512);
        async16(gB + i * 8 * S_, lB + i * 512);
    }

    int buf = 0;
    for (int kt = 0; kt < niter; kt++) {
        __syncthreads();
        if (kt + 1 < niter) {
            const int k0 = (kt + 1) * 64;
            const int nb = (buf ^ 1) * 8192;
            #pragma unroll
            for (int i = 0; i < 4; i++) {
                async16(gA + k0 + i * 8 * S_, lA + nb + i * 512);
                async16(gB + k0 + i * 8 * S_, lB + nb + i * 512);
            }
        }
        const unsigned short* Ac = As + buf * 8192;
        const unsigned short* Bc = Bs + buf * 8192;
        #pragma unroll
        for (int s = 0; s < 2; s++) {
            const int cs = ((s * 4 + quad) ^ l7) * 8;
            bf16x8 af[4], bfr[4];
            #pragma unroll
            for (int i = 0; i < 4; i++)
                af[i] = *(const bf16x8*)&Ac[(wm * 64 + i * 16 + l15) * 64 + cs];
            #pragma unroll
            for (int j = 0; j < 4; j++)
                bfr[j] = *(const bf16x8*)&Bc[(wn * 64 + j * 16 + l15) * 64 + cs];
            #pragma unroll
            for (int i = 0; i < 4; i++)
                #pragma unroll
                for (int j = 0; j < 4; j++)
                    acc[i][j] = __builtin_amdgcn_mfma_f32_16x16x32_bf16(af[i], bfr[j], acc[i][j], 0, 0, 0);
        }
        buf ^= 1;
    }

    // 1/rowsum for this wave's 64 rows (one per lane), off the critical front
    const int nsl = 2 * mt + 2;
    const float* rp = rowpart + (size_t)b * 32 * S_ + (m0 + wm * 64 + lane);
    float rsum = 0.f;
    for (int k = 0; k < nsl; k++) rsum += rp[(size_t)k * S_];
    const float invr = 1.0f / rsum;

    #pragma unroll
    for (int i = 0; i < 4; i++) {
        #pragma unroll
        for (int r = 0; r < 4; r++) {
            const float vr = __shfl(invr, i * 16 + quad * 4 + r);
            const int gm = m0 + wm * 64 + i * 16 + quad * 4 + r;
            #pragma unroll
            for (int j = 0; j < 4; j++) {
                const int gn = n0 + wn * 64 + j * 16 + l15;
                out[((size_t)b * S_ + gm) * D_ + gn] = rintf(acc[i][j][r] * vr * 1e4f) * 1e-4f;
            }
        }
    }
}

// ---------------------------------------------------------------------------
// Workspace layouts:
// FAT (needs 108.0 MB): Qb 16.7 | Kb 16.7 | Vt 16.7 | P 33.6 | rowpart 1.05 |
//   xb 16.8 | Wb 6.3   (no overlay — xb/Wb live through the fat kernel while
//   P is being written).
// FALLBACK (85 MB): as before — xb/Wb overlay the start of P (dead before
//   expscores writes P).
// ---------------------------------------------------------------------------
extern "C" void kernel_launch(void* const* d_in, const int* in_sizes, int n_in,
                              void* d_out, int out_size, void* d_ws, size_t ws_size,
                              hipStream_t stream)
{
    (void)in_sizes; (void)n_in; (void)out_size;
    const float* x  = (const float*)d_in[0];
    const float* Wk = (const float*)d_in[1];
    const float* Wq = (const float*)d_in[2];
    const float* Wv = (const float*)d_in[3];
    float* out = (float*)d_out;

    const size_t SD  = (size_t)B_ * S_ * D_;           // 8.39M elems
    const size_t SS  = (size_t)B_ * S_ * S_;           // 16.8M elems
    const size_t XBE = (size_t)B_ * S_ * E_;           // 8.39M elems
    const size_t WBE = (size_t)3 * D_ * E_;            // 3.15M elems
    const size_t RP  = (size_t)B_ * 32 * S_;           // fp32 elems

    const size_t need_fat = (3 * SD + SS + XBE + WBE) * 2 + RP * 4;  // 108.0 MB

    char* ws = (char*)d_ws;
    unsigned short* Qb = (unsigned short*)ws;
    unsigned short* Kb = Qb + SD;
    unsigned short* Vt = Kb + SD;
    unsigned short* P  = Vt + SD;
    unsigned short* xb;
    unsigned short* Wb;
    float* rowpart = (float*)(P + SS);

    const int conv_blocks = (B_ * S_ * E_ + 3 * D_ * E_) / (256 * 4);  // 11264

    if (ws_size >= need_fat) {
        xb = (unsigned short*)(rowpart + RP);
        Wb = xb + XBE;
        convert_kernel  <<<conv_blocks, 256, 0, stream>>>(x, Wk, Wq, Wv, xb, Wb);
        proj_kernel     <<<dim3(64, 16, 1),  256, 0, stream>>>(xb, Wb, Qb, Kb, Vt);  // KQ only
        fat_kernel      <<<dim3(1056, 1, 1), 256, 0, stream>>>(Qb, Kb, xb, Wb, P, rowpart, Vt);
        pv_kernel       <<<dim3(8, 16, B_),  256, 0, stream>>>(P, Vt, rowpart, out);
    } else {
        xb = P;                                  // overlay (dead before P write)
        Wb = xb + XBE;
        convert_kernel  <<<conv_blocks, 256, 0, stream>>>(x, Wk, Wq, Wv, xb, Wb);
        proj_kernel     <<<dim3(64, 24, 1),  256, 0, stream>>>(xb, Wb, Qb, Kb, Vt);
        expscores_kernel<<<dim3(16, 16, B_), 256, 0, stream>>>(Qb, Kb, P, rowpart);
        pv_kernel       <<<dim3(8, 16, B_),  256, 0, stream>>>(P, Vt, rowpart, out);
    }
}

// Round 4
// 219.015 us; speedup vs baseline: 1.0493x; 1.0297x over previous
//
#include <hip/hip_runtime.h>
#include <stdint.h>

#define B_ 4
#define S_ 2048
#define E_ 1024
#define D_ 1024   // attention dim

typedef short  bf16x8 __attribute__((ext_vector_type(8)));
typedef float  f32x4  __attribute__((ext_vector_type(4)));

// fp32 -> bf16 round-to-nearest-even
static __device__ __forceinline__ unsigned short f2bf(float f) {
    unsigned int u = __float_as_uint(f);
    u += 0x7fffu + ((u >> 16) & 1u);
    return (unsigned short)(u >> 16);
}

// async global->LDS, 16B per lane. LDS dest = wave-uniform base + lane*16.
static __device__ __forceinline__ void async16(const unsigned short* g, unsigned short* l) {
    auto gp = (const __attribute__((address_space(1))) void*)(uintptr_t)g;
    auto lp = (__attribute__((address_space(3))) void*)(uintptr_t)l;
    __builtin_amdgcn_global_load_lds(gp, lp, 16, 0, 0);
}

// ---------------------------------------------------------------------------
// LDS sub-tile unit (BK=64): row = 128 B = 8 chunks of 16 B. XOR swizzle:
// global chunk q of row r -> LDS chunk q^(r&7). One staging issue covers 8
// rows: lane l -> row +(l>>3), global chunk (l&7)^(l>>3). Reader k-half s:
// chunk (s*4+quad)^(row&7). Conflict-free (SQ_LDS_BANK_CONFLICT=0 measured).
//
// R4: fat kernel (R3) reverted — FETCH 134 MB vs 52 unique, L2 thrash,
// MfmaUtil 21%. Back to R1 structure (best 216 µs) + micro-fixes:
//   - exp: compact 136-block triangular grid (no dud blocks), heavy-first.
//   - pv: rowpart gather hoisted BEFORE the K-loop (latency hidden under
//     prologue staging instead of serial epilogue).
//   - convert: 2048-block grid-stride.
// Structural note: exp(544 jobs)/pv(512 jobs) are capped at ~2 blocks/CU by
// JOB COUNT with 128^2 tiles — their ~500 TF rate is the 2-resident regime.
// ---------------------------------------------------------------------------

// Kernel 0: fp32 -> bf16 convert (x -> xb, [Wk;Wq;Wv] -> Wb). Grid-stride.
__global__ __launch_bounds__(256)
void convert_kernel(const float* __restrict__ x,  const float* __restrict__ Wk,
                    const float* __restrict__ Wq, const float* __restrict__ Wv,
                    unsigned short* __restrict__ xb, unsigned short* __restrict__ Wb)
{
    const long long total  = (long long)B_ * S_ * E_ + 3LL * D_ * E_;  // 11534336
    const long long stride = (long long)gridDim.x * 256 * 4;
    for (long long idx = ((long long)blockIdx.x * 256 + threadIdx.x) * 4;
         idx < total; idx += stride) {
        const float* src; unsigned short* dst; long long off;
        if (idx < (long long)B_ * S_ * E_) {
            src = x; dst = xb; off = idx;
        } else {
            long long w = idx - (long long)B_ * S_ * E_;
            const int sel = (int)(w >> 20);          // 2^20 elems per W
            off = w & 1048575LL;
            src = (sel == 0) ? Wk : (sel == 1) ? Wq : Wv;
            dst = Wb + ((long long)sel << 20);
        }
        const float4 f = *(const float4*)(src + off);
        ushort4 u = { f2bf(f.x), f2bf(f.y), f2bf(f.z), f2bf(f.w) };
        *(ushort4*)(dst + off) = u;
    }
}

// ---------------------------------------------------------------------------
// Kernel 1: projections (FROZEN — 916 TF, the m97 plateau; 4 blocks/CU gives
// implicit overlap). C[m,n] = sum_e xb[m,e]*Wb[n,e]. Grid (64 m FAST, 24 ny).
// ---------------------------------------------------------------------------
__global__ __launch_bounds__(256, 4)
void proj_kernel(const unsigned short* __restrict__ xb,
                 const unsigned short* __restrict__ Wb,
                 unsigned short* __restrict__ Qb,
                 unsigned short* __restrict__ Kb,
                 unsigned short* __restrict__ Vt)
{
    __shared__ __align__(16) unsigned short As[128 * 64];
    __shared__ __align__(16) unsigned short Bs[128 * 64];

    const int t    = threadIdx.x;
    const int m0   = blockIdx.x * 128;
    const int ny   = blockIdx.y;
    const int wsel = ny >> 3;
    const int nloc = (ny & 7) * 128;

    const int lane = t & 63, wave = t >> 6;
    const int l15 = lane & 15, quad = lane >> 4;
    const int wm = wave & 1, wn = wave >> 1;
    const int sr = lane >> 3;
    const int sq = ((lane & 7) ^ sr) * 8;
    const int l7 = l15 & 7;
    const int rcA0 = (wm * 64 + l15) * 64 + ((quad ^ l7) * 8);
    const int rcA1 = (wm * 64 + l15) * 64 + (((4 + quad) ^ l7) * 8);
    const int rcB0 = (wn * 64 + l15) * 64 + ((quad ^ l7) * 8);
    const int rcB1 = (wn * 64 + l15) * 64 + (((4 + quad) ^ l7) * 8);

    const unsigned short* gA = xb + (size_t)(m0 + wave * 32 + sr) * E_ + sq;
    const unsigned short* gB = Wb + (size_t)(ny * 128 + wave * 32 + sr) * E_ + sq;
    unsigned short* lA = &As[wave * 2048];
    unsigned short* lB = &Bs[wave * 2048];

    f32x4 acc[4][4];
    #pragma unroll
    for (int i = 0; i < 4; i++)
        #pragma unroll
        for (int j = 0; j < 4; j++) acc[i][j] = {0.f, 0.f, 0.f, 0.f};

    for (int k0 = 0; k0 < E_; k0 += 64) {
        __syncthreads();
        #pragma unroll
        for (int i = 0; i < 4; i++) {
            async16(gA + k0 + i * 8 * E_, lA + i * 512);
            async16(gB + k0 + i * 8 * E_, lB + i * 512);
        }
        __syncthreads();

        #pragma unroll
        for (int s = 0; s < 2; s++) {
            bf16x8 af[4], bfr[4];
            const int ra = s ? rcA1 : rcA0, rb = s ? rcB1 : rcB0;
            #pragma unroll
            for (int i = 0; i < 4; i++) af[i]  = *(const bf16x8*)&As[ra + i * 1024];
            #pragma unroll
            for (int j = 0; j < 4; j++) bfr[j] = *(const bf16x8*)&Bs[rb + j * 1024];
            #pragma unroll
            for (int i = 0; i < 4; i++)
                #pragma unroll
                for (int j = 0; j < 4; j++)
                    acc[i][j] = __builtin_amdgcn_mfma_f32_16x16x32_bf16(af[i], bfr[j], acc[i][j], 0, 0, 0);
        }
    }

    if (wsel == 0) {
        #pragma unroll
        for (int i = 0; i < 4; i++)
            #pragma unroll
            for (int j = 0; j < 4; j++) {
                const int gn = nloc + wn * 64 + j * 16 + l15;
                #pragma unroll
                for (int r = 0; r < 4; r++) {
                    const int gm = m0 + wm * 64 + i * 16 + quad * 4 + r;
                    Kb[(size_t)gm * D_ + gn] = f2bf(acc[i][j][r]);
                }
            }
    } else if (wsel == 1) {
        #pragma unroll
        for (int i = 0; i < 4; i++)
            #pragma unroll
            for (int j = 0; j < 4; j++) {
                const int gn = nloc + wn * 64 + j * 16 + l15;
                #pragma unroll
                for (int r = 0; r < 4; r++) {
                    const int gm = m0 + wm * 64 + i * 16 + quad * 4 + r;
                    Qb[(size_t)gm * D_ + gn] = f2bf(acc[i][j][r] * 0.03125f);
                }
            }
    } else {
        #pragma unroll
        for (int i = 0; i < 4; i++)
            #pragma unroll
            for (int j = 0; j < 4; j++) {
                const int s0 = m0 + wm * 64 + i * 16 + quad * 4;
                const int b  = s0 >> 11, sl = s0 & (S_ - 1);
                const int gn = nloc + wn * 64 + j * 16 + l15;
                ushort4 u = { f2bf(acc[i][j][0]), f2bf(acc[i][j][1]),
                              f2bf(acc[i][j][2]), f2bf(acc[i][j][3]) };
                *(ushort4*)&Vt[((size_t)(b << 10) + gn) * S_ + sl] = u;
            }
    }
}

// ---------------------------------------------------------------------------
// Kernel 2: E = exp(Qs K^T), causal, bf16 -> P. 128x128 tile, BK=64,
// single-buffered 32 KB LDS. COMPACT grid (136 tri-tiles, B): heavy-first
// enumeration (mt=15 first), no dud blocks. Scores bounded (|s| ~< 2).
// rowpart[b][nt*2+wn][row].
// ---------------------------------------------------------------------------
__global__ __launch_bounds__(256, 4)
void expscores_kernel(const unsigned short* __restrict__ Qb,
                      const unsigned short* __restrict__ Kb,
                      unsigned short* __restrict__ P,
                      float* __restrict__ rowpart)
{
    // compact triangular decode, heavy-first: mt=15 has 16 tiles, mt=14 has
    // 15, ..., mt=0 has 1. Sum = 136.
    int rem = blockIdx.x;
    int mt = 15, cnt = 16;
    while (rem >= cnt) { rem -= cnt; mt--; cnt--; }
    const int nt = rem;
    const int b  = blockIdx.y;

    __shared__ __align__(16) unsigned short As[128 * 64];
    __shared__ __align__(16) unsigned short Bs[128 * 64];

    const int t = threadIdx.x;
    const int m0 = mt * 128, n0 = nt * 128;

    const int lane = t & 63, wave = t >> 6;
    const int l15 = lane & 15, quad = lane >> 4;
    const int wm = wave & 1, wn = wave >> 1;
    const int sr = lane >> 3;
    const int sq = ((lane & 7) ^ sr) * 8;
    const int l7 = l15 & 7;

    const unsigned short* gA = Qb + (size_t)b * S_ * D_ + (size_t)(m0 + wave * 32 + sr) * D_ + sq;
    const unsigned short* gB = Kb + (size_t)b * S_ * D_ + (size_t)(n0 + wave * 32 + sr) * D_ + sq;
    unsigned short* lA = &As[wave * 2048];
    unsigned short* lB = &Bs[wave * 2048];

    f32x4 acc[4][4];
    #pragma unroll
    for (int i = 0; i < 4; i++)
        #pragma unroll
        for (int j = 0; j < 4; j++) acc[i][j] = {0.f, 0.f, 0.f, 0.f};

    for (int kt = 0; kt < 16; kt++) {
        const int k0 = kt * 64;
        __syncthreads();
        #pragma unroll
        for (int i = 0; i < 4; i++) {
            async16(gA + k0 + i * 8 * D_, lA + i * 512);
            async16(gB + k0 + i * 8 * D_, lB + i * 512);
        }
        __syncthreads();

        #pragma unroll
        for (int s = 0; s < 2; s++) {
            const int cs = ((s * 4 + quad) ^ l7) * 8;
            bf16x8 af[4], bfr[4];
            #pragma unroll
            for (int i = 0; i < 4; i++)
                af[i] = *(const bf16x8*)&As[(wm * 64 + i * 16 + l15) * 64 + cs];
            #pragma unroll
            for (int j = 0; j < 4; j++)
                bfr[j] = *(const bf16x8*)&Bs[(wn * 64 + j * 16 + l15) * 64 + cs];
            #pragma unroll
            for (int i = 0; i < 4; i++)
                #pragma unroll
                for (int j = 0; j < 4; j++)
                    acc[i][j] = __builtin_amdgcn_mfma_f32_16x16x32_bf16(af[i], bfr[j], acc[i][j], 0, 0, 0);
        }
    }

    unsigned short* Pb = P + (size_t)b * S_ * S_;
    #pragma unroll
    for (int i = 0; i < 4; i++)
        #pragma unroll
        for (int j = 0; j < 4; j++) {
            const int gn = n0 + wn * 64 + j * 16 + l15;
            #pragma unroll
            for (int r = 0; r < 4; r++) {
                const int gm = m0 + wm * 64 + i * 16 + quad * 4 + r;
                const float e = (gn <= gm) ? __expf(acc[i][j][r]) : 0.f;
                acc[i][j][r] = e;
                Pb[(size_t)gm * S_ + gn] = f2bf(e);
            }
        }

    float* rp = rowpart + ((size_t)b * 32 + nt * 2 + wn) * S_;
    #pragma unroll
    for (int i = 0; i < 4; i++) {
        float rsub[4];
        #pragma unroll
        for (int r = 0; r < 4; r++) {
            float s = acc[i][0][r] + acc[i][1][r] + acc[i][2][r] + acc[i][3][r];
            #pragma unroll
            for (int off = 8; off; off >>= 1) s += __shfl_xor(s, off);
            rsub[r] = s;
        }
        if (l15 == 0) {
            #pragma unroll
            for (int r = 0; r < 4; r++)
                rp[m0 + wm * 64 + i * 16 + quad * 4 + r] = rsub[r];
        }
    }
}

// ---------------------------------------------------------------------------
// Kernel 3: out = (E @ V) / rowsum. 128x128 tile, BK=64, DOUBLE-BUFFERED
// (LDS 64 KB, 2 blocks/CU). Grid (8 nt FAST, 16 y, B); mt = (b&2)?y:15-y so
// co-resident pairs (c, c+256) have complementary iteration counts ->
// uniform 36 iters/CU. rowsum gather HOISTED before the K-loop (latency
// hides under prologue staging).
// ---------------------------------------------------------------------------
__global__ __launch_bounds__(256, 2)
void pv_kernel(const unsigned short* __restrict__ P,
               const unsigned short* __restrict__ Vt,
               const float* __restrict__ rowpart,
               float* __restrict__ out)
{
    const int nt = blockIdx.x;
    const int yy = blockIdx.y;
    const int b  = blockIdx.z;
    const int mt = (b & 2) ? yy : (15 - yy);  // complementary pairing across b

    __shared__ __align__(16) unsigned short As[2 * 128 * 64];
    __shared__ __align__(16) unsigned short Bs[2 * 128 * 64];

    const int t = threadIdx.x;
    const int m0 = mt * 128, n0 = nt * 128;
    const int niter = 2 * mt + 2;             // kend = m0+128, BK=64

    const int lane = t & 63, wave = t >> 6;
    const int l15 = lane & 15, quad = lane >> 4;
    const int wm = wave & 1, wn = wave >> 1;
    const int sr = lane >> 3;
    const int sq = ((lane & 7) ^ sr) * 8;
    const int l7 = l15 & 7;

    const unsigned short* gA = P  + (size_t)b * S_ * S_ + (size_t)(m0 + wave * 32 + sr) * S_ + sq;
    const unsigned short* gB = Vt + (size_t)b * D_ * S_ + (size_t)(n0 + wave * 32 + sr) * S_ + sq;
    unsigned short* lA = &As[wave * 2048];
    unsigned short* lB = &Bs[wave * 2048];

    // 1/rowsum gather for this wave's 64 rows — issued BEFORE the K-loop so
    // the ~2*mt scalar loads complete under the prologue staging.
    const float* rp = rowpart + (size_t)b * 32 * S_ + (m0 + wm * 64 + lane);
    float rsum = 0.f;
    for (int k = 0; k < niter; k++) rsum += rp[(size_t)k * S_];
    const float invr = 1.0f / rsum;

    f32x4 acc[4][4];
    #pragma unroll
    for (int i = 0; i < 4; i++)
        #pragma unroll
        for (int j = 0; j < 4; j++) acc[i][j] = {0.f, 0.f, 0.f, 0.f};

    // prologue: stage k=0 into buffer 0
    #pragma unroll
    for (int i = 0; i < 4; i++) {
        async16(gA + i * 8 * S_, lA + i * 512);
        async16(gB + i * 8 * S_, lB + i * 512);
    }

    int buf = 0;
    for (int kt = 0; kt < niter; kt++) {
        __syncthreads();
        if (kt + 1 < niter) {
            const int k0 = (kt + 1) * 64;
            const int nb = (buf ^ 1) * 8192;
            #pragma unroll
            for (int i = 0; i < 4; i++) {
                async16(gA + k0 + i * 8 * S_, lA + nb + i * 512);
                async16(gB + k0 + i * 8 * S_, lB + nb + i * 512);
            }
        }
        const unsigned short* Ac = As + buf * 8192;
        const unsigned short* Bc = Bs + buf * 8192;
        #pragma unroll
        for (int s = 0; s < 2; s++) {
            const int cs = ((s * 4 + quad) ^ l7) * 8;
            bf16x8 af[4], bfr[4];
            #pragma unroll
            for (int i = 0; i < 4; i++)
                af[i] = *(const bf16x8*)&Ac[(wm * 64 + i * 16 + l15) * 64 + cs];
            #pragma unroll
            for (int j = 0; j < 4; j++)
                bfr[j] = *(const bf16x8*)&Bc[(wn * 64 + j * 16 + l15) * 64 + cs];
            #pragma unroll
            for (int i = 0; i < 4; i++)
                #pragma unroll
                for (int j = 0; j < 4; j++)
                    acc[i][j] = __builtin_amdgcn_mfma_f32_16x16x32_bf16(af[i], bfr[j], acc[i][j], 0, 0, 0);
        }
        buf ^= 1;
    }

    #pragma unroll
    for (int i = 0; i < 4; i++) {
        #pragma unroll
        for (int r = 0; r < 4; r++) {
            const float vr = __shfl(invr, i * 16 + quad * 4 + r);
            const int gm = m0 + wm * 64 + i * 16 + quad * 4 + r;
            #pragma unroll
            for (int j = 0; j < 4; j++) {
                const int gn = n0 + wn * 64 + j * 16 + l15;
                out[((size_t)b * S_ + gm) * D_ + gn] = rintf(acc[i][j][r] * vr * 1e4f) * 1e-4f;
            }
        }
    }
}

// ---------------------------------------------------------------------------
// Workspace (~85 MB):
//   [0,     16.7M)  Qb bf16 [4][2048][1024]
//   [16.7M, 33.5M)  Kb bf16
//   [33.5M, 50.3M)  Vt bf16 [4][1024][2048]
//   [50.3M, 83.9M)  P  bf16 [4][2048][2048]
//       xb (16.7M) + Wb (6.3M) overlay the start of P's region (dead before
//       expscores writes P).
//   [83.9M, +1M)    rowpart fp32 [4][32][2048]
// ---------------------------------------------------------------------------
extern "C" void kernel_launch(void* const* d_in, const int* in_sizes, int n_in,
                              void* d_out, int out_size, void* d_ws, size_t ws_size,
                              hipStream_t stream)
{
    (void)in_sizes; (void)n_in; (void)out_size; (void)ws_size;
    const float* x  = (const float*)d_in[0];
    const float* Wk = (const float*)d_in[1];
    const float* Wq = (const float*)d_in[2];
    const float* Wv = (const float*)d_in[3];
    float* out = (float*)d_out;

    char* ws = (char*)d_ws;
    unsigned short* Qb = (unsigned short*)ws;
    unsigned short* Kb = Qb + (size_t)B_ * S_ * D_;
    unsigned short* Vt = Kb + (size_t)B_ * S_ * D_;
    unsigned short* P  = Vt + (size_t)B_ * D_ * S_;
    unsigned short* xb = P;                                  // overlay (dead early)
    unsigned short* Wb = xb + (size_t)B_ * S_ * E_;
    float* rowpart = (float*)(P + (size_t)B_ * S_ * S_);

    convert_kernel  <<<2048, 256, 0, stream>>>(x, Wk, Wq, Wv, xb, Wb);
    proj_kernel     <<<dim3(64, 24, 1),  256, 0, stream>>>(xb, Wb, Qb, Kb, Vt);
    expscores_kernel<<<dim3(136, B_, 1), 256, 0, stream>>>(Qb, Kb, P, rowpart);
    pv_kernel       <<<dim3(8, 16, B_),  256, 0, stream>>>(P, Vt, rowpart, out);
}